// Round 1
// 203.431 us; speedup vs baseline: 1.1324x; 1.1324x over previous
//
#include <hip/hip_runtime.h>
#include <math.h>

#define NN 100000
#define DI 64
#define DH 128
#define DO 40

#define NBUCK 512
#define NPB 196          // nodes per bucket: 512*196 = 100352 >= 100000
#define CAP 3712         // bucket capacity: mean 3125 + ~10.5 sigma
#define CAPP 4352        // padded col capacity: CAP + NPB*3, rounded to 64
#define EPB 4096         // edges per scatter block
#define TPB_S 512        // threads per scatter/setup block
#define KE (EPB / TPB_S) // edges per thread = 8

typedef __attribute__((ext_vector_type(8))) short bf16x8;
typedef __attribute__((ext_vector_type(4))) float f32x4;
typedef __attribute__((ext_vector_type(2))) float f32x2;

__device__ __forceinline__ unsigned short bf16r(float a) {
    unsigned u = __float_as_uint(a);
    u = (u + 0x7FFF + ((u >> 16) & 1)) >> 16;
    return (unsigned short)u;
}
__device__ __forceinline__ unsigned bf16pair(float a, float b) {
    return (unsigned)bf16r(a) | ((unsigned)bf16r(b) << 16);
}
__device__ __forceinline__ float bflo(unsigned u) { return __uint_as_float(u << 16); }
__device__ __forceinline__ float bfhi(unsigned u) { return __uint_as_float(u & 0xFFFF0000u); }

// ---------- fused: scatter blocks [0,nbe) + setup blocks [nbe, nbe+nsetup) ----------
// bcur is zero-initialized by hipMemsetAsync; holds per-bucket COUNTS (base i*CAP
// added at reservation time), so scatter no longer depends on setup.
__global__ __launch_bounds__(TPB_S) void setup_scatter_kernel(
        const float* __restrict__ x, const float* __restrict__ W1l,
        const float* __restrict__ W1r, const float* __restrict__ W2l,
        const float* __restrict__ W2r,
        unsigned* __restrict__ xb, unsigned short* __restrict__ WB1,
        unsigned short* __restrict__ WB2, unsigned* __restrict__ p2,
        const int* __restrict__ src, const int* __restrict__ dst,
        int* __restrict__ bcur, int* __restrict__ eb,
        int nbe, int E, int N) {
    __shared__ int h[NBUCK];
    int t = threadIdx.x;
    if ((int)blockIdx.x < nbe) {
        // ---- bucket scatter: eb[pos] = (local<<17)|src ----
        if (t < NBUCK) h[t] = 0;
        __syncthreads();
        int base = blockIdx.x * EPB;
        int end = base + EPB; if (end > E) end = E;
        int dloc[KE];
#pragma unroll
        for (int k = 0; k < KE; k++) {
            int i = base + t + k * TPB_S;
            dloc[k] = (i < end) ? dst[i] : -1;
        }
#pragma unroll
        for (int k = 0; k < KE; k++)
            if (dloc[k] >= 0) atomicAdd(&h[(unsigned)dloc[k] / NPB], 1);
        __syncthreads();
        if (t < NBUCK) {
            int v = h[t];
            h[t] = v ? (atomicAdd(&bcur[t], v) + t * CAP) : 0;
        }
        __syncthreads();
#pragma unroll
        for (int k = 0; k < KE; k++) {
            int d = dloc[k];
            if (d >= 0) {
                unsigned bk = (unsigned)d / NPB;
                int local = d - (int)bk * NPB;
                int pos = atomicAdd(&h[bk], 1);
                eb[pos] = (local << 17) | src[base + t + k * TPB_S];
            }
        }
    } else {
        // ---- setup: x->bf16, weight packs, p2 dummy row ----
        int idx = (blockIdx.x - nbe) * TPB_S + t;
        if (idx < (N + 1) * 32) {
            if (idx < N * 32) {
                float2 f = ((const float2*)x)[idx];
                xb[idx] = bf16pair(f.x, f.y);
            } else {
                xb[idx] = 0;          // dummy row N of xb
            }
        }
        if (idx < 16384) {
            int j = idx & 7, lane = (idx >> 3) & 63, ks = (idx >> 9) & 3, nt = idx >> 11;
            int k = ks * 32 + (lane >> 4) * 8 + j;
            int n = nt * 16 + (lane & 15);
            float v = (k < DI) ? W1l[n * DI + k] : W1r[n * DI + (k - DI)];
            WB1[idx] = bf16r(v);
        }
        if (idx >= 16384 && idx < 16384 + 10240) {
            int idx2 = idx - 16384;
            int j = idx2 & 7, lane = (idx2 >> 3) & 63, ks = (idx2 >> 9) & 3, nt = idx2 >> 11;
            int k = ks * 32 + (lane >> 4) * 8 + j;
            int n = nt * 16 + (lane & 15);
            float v = (n < DO) ? W2l[n * DH + k] : W2r[(n - DO) * DH + k];
            WB2[idx2] = bf16r(v);
        }
        if (idx < 10) p2[(size_t)N * 10 + idx] = 0;   // dummy fp8 row N (decodes to 0)
    }
}

// ---------- fill: per bucket -> rowptr/cnt/inv + col padded to x4 with dummy NN ----------
__global__ __launch_bounds__(256) void bucket_fill_kernel(const int* __restrict__ eb,
                                                          const int* __restrict__ bend,
                                                          int* __restrict__ rowptr,
                                                          int* __restrict__ cntg,
                                                          float* __restrict__ inv,
                                                          int* __restrict__ col, int N) {
    __shared__ int scnt[256];
    __shared__ int scur[256];
    __shared__ int sbase[256];
    int b = blockIdx.x, t = threadIdx.x;
    int ebeg = b * CAP, eend = ebeg + bend[b];   // bend holds counts now
    scnt[t] = 0;
    __syncthreads();
    for (int i = ebeg + t; i < eend; i += 256)
        atomicAdd(&scnt[eb[i] >> 17], 1);
    __syncthreads();
    int myc = scnt[t];
    int pc = (myc + 3) & ~3;
    scnt[t] = pc;
    __syncthreads();
    for (int off = 1; off < 256; off <<= 1) {
        int tmp = (t >= off) ? scnt[t - off] : 0;
        __syncthreads();
        scnt[t] += tmp;
        __syncthreads();
    }
    int excl = scnt[t] - pc;
    int base = b * CAPP + excl;
    int node = b * NPB + t;
    if (t < NPB && node < N) {
        rowptr[node] = base;
        cntg[node] = myc;
        inv[node] = 1.0f / (float)(myc > 0 ? myc : 1);
    }
    scur[t] = base;
    sbase[t] = base;
    __syncthreads();
    for (int i = ebeg + t; i < eend; i += 256) {
        int pk = eb[i];
        int pos = atomicAdd(&scur[pk >> 17], 1);
        col[pos] = pk & 0x1FFFF;
    }
    __syncthreads();
    if (t < NPB) {
        int bs = sbase[t];
        for (int i = myc; i < pc; i++) col[bs + i] = NN;
    }
}

// ---------- agg1: 8 lanes per node, 8 nodes/wave, sequential edges 4-wide ----------
__global__ void agg1_kernel(const unsigned* __restrict__ xb, const int* __restrict__ rowptr,
                            const int* __restrict__ cnt, const float* __restrict__ inv,
                            const int* __restrict__ col, unsigned* __restrict__ xa, int N) {
    int n = (blockIdx.x * 256 + threadIdx.x) >> 3;
    int chunk = threadIdx.x & 7;
    if (n >= N) return;
    int beg = rowptr[n], deg = cnt[n];
    int degp = (deg + 3) & ~3;
    float a[8];
#pragma unroll
    for (int j = 0; j < 8; j++) a[j] = 0.f;
    for (int i = 0; i < degp; i += 4) {
        int s0 = col[beg + i], s1 = col[beg + i + 1];
        int s2 = col[beg + i + 2], s3 = col[beg + i + 3];
        uint4 u0 = *(const uint4*)(xb + (size_t)s0 * 32 + chunk * 4);
        uint4 u1 = *(const uint4*)(xb + (size_t)s1 * 32 + chunk * 4);
        uint4 u2 = *(const uint4*)(xb + (size_t)s2 * 32 + chunk * 4);
        uint4 u3 = *(const uint4*)(xb + (size_t)s3 * 32 + chunk * 4);
        a[0] += bflo(u0.x) + bflo(u1.x) + bflo(u2.x) + bflo(u3.x);
        a[1] += bfhi(u0.x) + bfhi(u1.x) + bfhi(u2.x) + bfhi(u3.x);
        a[2] += bflo(u0.y) + bflo(u1.y) + bflo(u2.y) + bflo(u3.y);
        a[3] += bfhi(u0.y) + bfhi(u1.y) + bfhi(u2.y) + bfhi(u3.y);
        a[4] += bflo(u0.z) + bflo(u1.z) + bflo(u2.z) + bflo(u3.z);
        a[5] += bfhi(u0.z) + bfhi(u1.z) + bfhi(u2.z) + bfhi(u3.z);
        a[6] += bflo(u0.w) + bflo(u1.w) + bflo(u2.w) + bflo(u3.w);
        a[7] += bfhi(u0.w) + bfhi(u1.w) + bfhi(u2.w) + bfhi(u3.w);
    }
    float invn = inv[n];
    uint4 o;
    o.x = bf16pair(a[0] * invn, a[1] * invn);
    o.y = bf16pair(a[2] * invn, a[3] * invn);
    o.z = bf16pair(a[4] * invn, a[5] * invn);
    o.w = bf16pair(a[6] * invn, a[7] * invn);
    *(uint4*)(xa + (size_t)n * 64 + chunk * 4) = o;
    uint4 u = *(const uint4*)(xb + (size_t)n * 32 + chunk * 4);
    *(uint4*)(xa + (size_t)n * 64 + 32 + chunk * 4) = u;
}

// ---------- fused GEMM1+GEMM2: h stays in LDS (64x136 bf16, bank-balanced) ----------
__global__ __launch_bounds__(256) void gemm12_kernel(const unsigned short* __restrict__ xa,
                                                     const unsigned short* __restrict__ WB1,
                                                     const float* __restrict__ b1,
                                                     const unsigned short* __restrict__ WB2,
                                                     const float* __restrict__ b2,
                                                     unsigned* __restrict__ p2,
                                                     float* __restrict__ selfp, int N) {
    __shared__ unsigned short hs[64][136];   // +8 shorts pad -> 17 chunks/row, balanced
    __shared__ float st[64][41];
    int w = threadIdx.x >> 6, lane = threadIdx.x & 63;
    int quad = lane >> 4, m = lane & 15;
    int rbase = blockIdx.x * 64 + w * 16;
    int arow = rbase + m; if (arow >= N) arow = N - 1;
    int lw = w * 16;

    // GEMM1: h = relu(xa @ Wcat1 + b1) -> LDS
    f32x4 acc[8];
#pragma unroll
    for (int nt = 0; nt < 8; nt++) acc[nt] = (f32x4)(0.f);
#pragma unroll
    for (int ks = 0; ks < 4; ks++) {
        bf16x8 a = *(const bf16x8*)(xa + (size_t)arow * 128 + ks * 32 + quad * 8);
#pragma unroll
        for (int nt = 0; nt < 8; nt++) {
            bf16x8 b = *(const bf16x8*)(WB1 + ((size_t)(nt * 4 + ks) * 64 + lane) * 8);
            acc[nt] = __builtin_amdgcn_mfma_f32_16x16x32_bf16(a, b, acc[nt], 0, 0, 0);
        }
    }
#pragma unroll
    for (int nt = 0; nt < 8; nt++) {
        int colj = nt * 16 + m;
        float bj = b1[colj];
#pragma unroll
        for (int r = 0; r < 4; r++) {
            hs[lw + quad * 4 + r][colj] = bf16r(fmaxf(acc[nt][r] + bj, 0.f));
        }
    }
    __syncthreads();

    // GEMM2: p2 (40 fp8/row) + selfp (40 f32) = h @ Wcat2
    f32x4 acc2[5];
#pragma unroll
    for (int nt = 0; nt < 5; nt++) acc2[nt] = (f32x4)(0.f);
#pragma unroll
    for (int ks = 0; ks < 4; ks++) {
        bf16x8 a = *(const bf16x8*)(&hs[lw + m][ks * 32 + quad * 8]);
#pragma unroll
        for (int nt = 0; nt < 5; nt++) {
            bf16x8 b = *(const bf16x8*)(WB2 + ((size_t)(nt * 4 + ks) * 64 + lane) * 8);
            acc2[nt] = __builtin_amdgcn_mfma_f32_16x16x32_bf16(a, b, acc2[nt], 0, 0, 0);
        }
    }
#pragma unroll
    for (int nt = 0; nt < 5; nt++) {
        int colj = nt * 16 + m;
#pragma unroll
        for (int r = 0; r < 4; r++) {
            int lrow = lw + quad * 4 + r;
            int row = rbase + quad * 4 + r;
            float v = acc2[nt][r];
            if (colj < 40) {
                st[lrow][colj] = v;
            } else if (row < N) {
                selfp[(size_t)row * 40 + (colj - 40)] = v + b2[colj - 40];
            }
        }
    }
    __syncthreads();
    for (int i = threadIdx.x; i < 64 * 10; i += 256) {
        int lr = i / 10, dw = i - lr * 10;
        int grow = blockIdx.x * 64 + lr;
        if (grow < N) {
            float v0 = st[lr][dw * 4 + 0], v1 = st[lr][dw * 4 + 1];
            float v2 = st[lr][dw * 4 + 2], v3 = st[lr][dw * 4 + 3];
            unsigned u = __builtin_amdgcn_cvt_pk_fp8_f32(v0, v1, 0u, false);
            u = __builtin_amdgcn_cvt_pk_fp8_f32(v2, v3, u, true);
            p2[(size_t)grow * 10 + dw] = u;
        }
    }
}

// ---------- agg2 + log_softmax: 8 lanes/node (5 active), sequential edges 4-wide ----------
__global__ void agg2_softmax_kernel(const unsigned* __restrict__ p2,
                                    const float* __restrict__ selfp,
                                    const int* __restrict__ rowptr,
                                    const int* __restrict__ cnt,
                                    const float* __restrict__ inv,
                                    const int* __restrict__ col,
                                    float* __restrict__ out, int N) {
    int n = (blockIdx.x * 256 + threadIdx.x) >> 3;
    int chunk = threadIdx.x & 7;
    if (n >= N) return;
    int beg = rowptr[n], deg = cnt[n];
    int degp = (deg + 3) & ~3;
    bool vc = (chunk < 5);
    float a[8];
#pragma unroll
    for (int j = 0; j < 8; j++) a[j] = 0.f;
    for (int i = 0; i < degp; i += 4) {
        int s0 = col[beg + i], s1 = col[beg + i + 1];
        int s2 = col[beg + i + 2], s3 = col[beg + i + 3];
        if (vc) {
            uint2 u0 = *(const uint2*)(p2 + (size_t)s0 * 10 + chunk * 2);
            uint2 u1 = *(const uint2*)(p2 + (size_t)s1 * 10 + chunk * 2);
            uint2 u2 = *(const uint2*)(p2 + (size_t)s2 * 10 + chunk * 2);
            uint2 u3 = *(const uint2*)(p2 + (size_t)s3 * 10 + chunk * 2);
            f32x2 d;
            d = __builtin_amdgcn_cvt_pk_f32_fp8(u0.x, false); a[0] += d.x; a[1] += d.y;
            d = __builtin_amdgcn_cvt_pk_f32_fp8(u0.x, true);  a[2] += d.x; a[3] += d.y;
            d = __builtin_amdgcn_cvt_pk_f32_fp8(u0.y, false); a[4] += d.x; a[5] += d.y;
            d = __builtin_amdgcn_cvt_pk_f32_fp8(u0.y, true);  a[6] += d.x; a[7] += d.y;
            d = __builtin_amdgcn_cvt_pk_f32_fp8(u1.x, false); a[0] += d.x; a[1] += d.y;
            d = __builtin_amdgcn_cvt_pk_f32_fp8(u1.x, true);  a[2] += d.x; a[3] += d.y;
            d = __builtin_amdgcn_cvt_pk_f32_fp8(u1.y, false); a[4] += d.x; a[5] += d.y;
            d = __builtin_amdgcn_cvt_pk_f32_fp8(u1.y, true);  a[6] += d.x; a[7] += d.y;
            d = __builtin_amdgcn_cvt_pk_f32_fp8(u2.x, false); a[0] += d.x; a[1] += d.y;
            d = __builtin_amdgcn_cvt_pk_f32_fp8(u2.x, true);  a[2] += d.x; a[3] += d.y;
            d = __builtin_amdgcn_cvt_pk_f32_fp8(u2.y, false); a[4] += d.x; a[5] += d.y;
            d = __builtin_amdgcn_cvt_pk_f32_fp8(u2.y, true);  a[6] += d.x; a[7] += d.y;
            d = __builtin_amdgcn_cvt_pk_f32_fp8(u3.x, false); a[0] += d.x; a[1] += d.y;
            d = __builtin_amdgcn_cvt_pk_f32_fp8(u3.x, true);  a[2] += d.x; a[3] += d.y;
            d = __builtin_amdgcn_cvt_pk_f32_fp8(u3.y, false); a[4] += d.x; a[5] += d.y;
            d = __builtin_amdgcn_cvt_pk_f32_fp8(u3.y, true);  a[6] += d.x; a[7] += d.y;
        }
    }
    float invn = inv[n];
    float v[8];
    if (vc) {
        float4 s0 = *(const float4*)(selfp + (size_t)n * DO + chunk * 8);
        float4 s1 = *(const float4*)(selfp + (size_t)n * DO + chunk * 8 + 4);
        v[0] = a[0] * invn + s0.x; v[1] = a[1] * invn + s0.y;
        v[2] = a[2] * invn + s0.z; v[3] = a[3] * invn + s0.w;
        v[4] = a[4] * invn + s1.x; v[5] = a[5] * invn + s1.y;
        v[6] = a[6] * invn + s1.z; v[7] = a[7] * invn + s1.w;
    } else {
#pragma unroll
        for (int j = 0; j < 8; j++) v[j] = 0.f;
    }
    float mv = -INFINITY;
    if (vc) {
#pragma unroll
        for (int j = 0; j < 8; j++) mv = fmaxf(mv, v[j]);
    }
#pragma unroll
    for (int off = 1; off <= 4; off <<= 1) mv = fmaxf(mv, __shfl_xor(mv, off, 8));
    float es = 0.f;
    if (vc) {
#pragma unroll
        for (int j = 0; j < 8; j++) es += expf(v[j] - mv);
    }
#pragma unroll
    for (int off = 1; off <= 4; off <<= 1) es += __shfl_xor(es, off, 8);
    if (vc) {
        float ls = mv + logf(es);
        float4 o0, o1;
        o0.x = v[0] - ls; o0.y = v[1] - ls; o0.z = v[2] - ls; o0.w = v[3] - ls;
        o1.x = v[4] - ls; o1.y = v[5] - ls; o1.z = v[6] - ls; o1.w = v[7] - ls;
        *(float4*)(out + (size_t)n * DO + chunk * 8) = o0;
        *(float4*)(out + (size_t)n * DO + chunk * 8 + 4) = o1;
    }
}

extern "C" void kernel_launch(void* const* d_in, const int* in_sizes, int n_in,
                              void* d_out, int out_size, void* d_ws, size_t ws_size,
                              hipStream_t stream) {
    const float* x   = (const float*)d_in[0];
    const int*  ei   = (const int*)d_in[1];
    const float* W1l = (const float*)d_in[2];
    const float* b1  = (const float*)d_in[3];
    const float* W1r = (const float*)d_in[4];
    const float* W2l = (const float*)d_in[5];
    const float* b2  = (const float*)d_in[6];
    const float* W2r = (const float*)d_in[7];
    float* out = (float*)d_out;

    const int E = in_sizes[1] / 2;
    const int N = NN;
    const int* src = ei;
    const int* dst = ei + E;
    const int nbe = (E + EPB - 1) / EPB;
    const int nsetup = ((N + 1) * 32 + TPB_S - 1) / TPB_S;

    size_t off = 0;
    auto alloc = [&](size_t nf) { size_t o = off; off += (nf + 63) & ~(size_t)63; return o; };
    size_t o_bcur   = alloc(NBUCK);                   // int (counts, memset to 0)
    size_t o_eb     = alloc((size_t)NBUCK * CAP);     // int
    size_t o_col    = alloc((size_t)NBUCK * CAPP);    // int (padded CSR col)
    size_t o_rowptr = alloc(N);                       // int
    size_t o_cnt    = alloc(N);                       // int
    size_t o_inv    = alloc(N);                       // f32
    size_t o_xb     = alloc((size_t)(N + 1) * 32);    // u32 (64 bf16/row, +dummy)
    size_t o_xa     = alloc((size_t)N * 64);          // u32 (128 bf16/row)
    size_t o_p2     = alloc((size_t)(N + 1) * 10);    // u32 (40 fp8/row, +dummy) = 4MB
    size_t o_selfp  = alloc((size_t)N * DO);          // f32
    size_t o_wb1    = alloc(16384 / 2);
    size_t o_wb2    = alloc(10240 / 2);
    (void)ws_size;

    float* ws = (float*)d_ws;
    int* bcur   = (int*)(ws + o_bcur);
    int* eb     = (int*)(ws + o_eb);
    int* col    = (int*)(ws + o_col);
    int* rowptr = (int*)(ws + o_rowptr);
    int* cnt    = (int*)(ws + o_cnt);
    float* inv  = ws + o_inv;
    unsigned* xb = (unsigned*)(ws + o_xb);
    unsigned* xa = (unsigned*)(ws + o_xa);
    unsigned* p2 = (unsigned*)(ws + o_p2);
    float* selfp = ws + o_selfp;
    unsigned short* WB1 = (unsigned short*)(ws + o_wb1);
    unsigned short* WB2 = (unsigned short*)(ws + o_wb2);

    hipMemsetAsync(bcur, 0, NBUCK * sizeof(int), stream);

    setup_scatter_kernel<<<nbe + nsetup, TPB_S, 0, stream>>>(
        x, W1l, W1r, W2l, W2r, xb, WB1, WB2, p2, src, dst, bcur, eb, nbe, E, N);

    bucket_fill_kernel<<<NBUCK, 256, 0, stream>>>(eb, bcur, rowptr, cnt, inv, col, N);

    agg1_kernel<<<(N * 8 + 255) / 256, 256, 0, stream>>>(xb, rowptr, cnt, inv, col, xa, N);
    gemm12_kernel<<<(N + 63) / 64, 256, 0, stream>>>((const unsigned short*)xa, WB1, b1,
                                                     WB2, b2, p2, selfp, N);
    agg2_softmax_kernel<<<(N * 8 + 255) / 256, 256, 0, stream>>>(p2, selfp, rowptr, cnt, inv, col, out, N);
}

// Round 2
// 199.609 us; speedup vs baseline: 1.1541x; 1.0192x over previous
//
#include <hip/hip_runtime.h>
#include <math.h>

#define NN 100000
#define DI 64
#define DH 128
#define DO 40

#define NBUCK 512
#define NPB 196          // nodes per bucket: 512*196 = 100352 >= 100000
#define CAP 3712         // bucket capacity: mean 3125 + ~10.5 sigma
#define CAPP 4352        // padded col capacity: CAP + NPB*3, rounded to 64
#define EPB 4096         // edges per scatter block
#define TPB_S 512        // threads per scatter/setup block
#define KE (EPB / TPB_S) // edges per thread = 8

typedef __attribute__((ext_vector_type(8))) short bf16x8;
typedef __attribute__((ext_vector_type(4))) float f32x4;
typedef __attribute__((ext_vector_type(2))) float f32x2;

__device__ __forceinline__ unsigned short bf16r(float a) {
    unsigned u = __float_as_uint(a);
    u = (u + 0x7FFF + ((u >> 16) & 1)) >> 16;
    return (unsigned short)u;
}
__device__ __forceinline__ unsigned bf16pair(float a, float b) {
    return (unsigned)bf16r(a) | ((unsigned)bf16r(b) << 16);
}
__device__ __forceinline__ float bflo(unsigned u) { return __uint_as_float(u << 16); }
__device__ __forceinline__ float bfhi(unsigned u) { return __uint_as_float(u & 0xFFFF0000u); }

// ---------- fused: scatter blocks [0,nbe) + setup blocks [nbe, nbe+nsetup) ----------
// bcur is zero-initialized by hipMemsetAsync; holds per-bucket COUNTS (base i*CAP
// added at reservation time), so scatter no longer depends on setup.
__global__ __launch_bounds__(TPB_S) void setup_scatter_kernel(
        const float* __restrict__ x, const float* __restrict__ W1l,
        const float* __restrict__ W1r, const float* __restrict__ W2l,
        const float* __restrict__ W2r,
        unsigned* __restrict__ xb, unsigned short* __restrict__ WB1,
        unsigned short* __restrict__ WB2, unsigned* __restrict__ p2,
        const int* __restrict__ src, const int* __restrict__ dst,
        int* __restrict__ bcur, int* __restrict__ eb,
        int nbe, int E, int N) {
    __shared__ int h[NBUCK];
    int t = threadIdx.x;
    if ((int)blockIdx.x < nbe) {
        // ---- bucket scatter: eb[pos] = (local<<17)|src ----
        if (t < NBUCK) h[t] = 0;
        __syncthreads();
        int base = blockIdx.x * EPB;
        int end = base + EPB; if (end > E) end = E;
        int dloc[KE];
#pragma unroll
        for (int k = 0; k < KE; k++) {
            int i = base + t + k * TPB_S;
            dloc[k] = (i < end) ? dst[i] : -1;
        }
#pragma unroll
        for (int k = 0; k < KE; k++)
            if (dloc[k] >= 0) atomicAdd(&h[(unsigned)dloc[k] / NPB], 1);
        __syncthreads();
        if (t < NBUCK) {
            int v = h[t];
            h[t] = v ? (atomicAdd(&bcur[t], v) + t * CAP) : 0;
        }
        __syncthreads();
#pragma unroll
        for (int k = 0; k < KE; k++) {
            int d = dloc[k];
            if (d >= 0) {
                unsigned bk = (unsigned)d / NPB;
                int local = d - (int)bk * NPB;
                int pos = atomicAdd(&h[bk], 1);
                eb[pos] = (local << 17) | src[base + t + k * TPB_S];
            }
        }
    } else {
        // ---- setup: x->bf16, weight packs, p2 dummy row ----
        int idx = (blockIdx.x - nbe) * TPB_S + t;
        if (idx < (N + 1) * 32) {
            if (idx < N * 32) {
                float2 f = ((const float2*)x)[idx];
                xb[idx] = bf16pair(f.x, f.y);
            } else {
                xb[idx] = 0;          // dummy row N of xb
            }
        }
        if (idx < 16384) {
            int j = idx & 7, lane = (idx >> 3) & 63, ks = (idx >> 9) & 3, nt = idx >> 11;
            int k = ks * 32 + (lane >> 4) * 8 + j;
            int n = nt * 16 + (lane & 15);
            float v = (k < DI) ? W1l[n * DI + k] : W1r[n * DI + (k - DI)];
            WB1[idx] = bf16r(v);
        }
        if (idx >= 16384 && idx < 16384 + 10240) {
            int idx2 = idx - 16384;
            int j = idx2 & 7, lane = (idx2 >> 3) & 63, ks = (idx2 >> 9) & 3, nt = idx2 >> 11;
            int k = ks * 32 + (lane >> 4) * 8 + j;
            int n = nt * 16 + (lane & 15);
            float v = (n < DO) ? W2l[n * DH + k] : W2r[(n - DO) * DH + k];
            WB2[idx2] = bf16r(v);
        }
        if (idx < 10) p2[(size_t)N * 10 + idx] = 0;   // dummy fp8 row N (decodes to 0)
    }
}

// ---------- fill: per bucket -> rowptr/cnt/inv + col padded to x4 with dummy NN ----------
__global__ __launch_bounds__(256) void bucket_fill_kernel(const int* __restrict__ eb,
                                                          const int* __restrict__ bend,
                                                          int* __restrict__ rowptr,
                                                          int* __restrict__ cntg,
                                                          float* __restrict__ inv,
                                                          int* __restrict__ col, int N) {
    __shared__ int scnt[256];
    __shared__ int scur[256];
    __shared__ int sbase[256];
    int b = blockIdx.x, t = threadIdx.x;
    int ebeg = b * CAP, eend = ebeg + bend[b];   // bend holds counts
    scnt[t] = 0;
    __syncthreads();
    for (int i = ebeg + t; i < eend; i += 256)
        atomicAdd(&scnt[eb[i] >> 17], 1);
    __syncthreads();
    int myc = scnt[t];
    int pc = (myc + 3) & ~3;
    scnt[t] = pc;
    __syncthreads();
    for (int off = 1; off < 256; off <<= 1) {
        int tmp = (t >= off) ? scnt[t - off] : 0;
        __syncthreads();
        scnt[t] += tmp;
        __syncthreads();
    }
    int excl = scnt[t] - pc;
    int base = b * CAPP + excl;
    int node = b * NPB + t;
    if (t < NPB && node < N) {
        rowptr[node] = base;
        cntg[node] = myc;
        inv[node] = 1.0f / (float)(myc > 0 ? myc : 1);
    }
    scur[t] = base;
    sbase[t] = base;
    __syncthreads();
    for (int i = ebeg + t; i < eend; i += 256) {
        int pk = eb[i];
        int pos = atomicAdd(&scur[pk >> 17], 1);
        col[pos] = pk & 0x1FFFF;
    }
    __syncthreads();
    if (t < NPB) {
        int bs = sbase[t];
        for (int i = myc; i < pc; i++) col[bs + i] = NN;
    }
}

// ---------- fused agg1 + GEMM1 + GEMM2: per block of 64 nodes ----------
// Phase A: 32 groups x 8 lanes aggregate into LDS A-tile sh[64][136]
//          (cols 0..63 = mean-agg bf16, cols 64..127 = self features from xb).
// Phase B: GEMM1 h=relu(A@Wcat1+b1) -> sh (in place, barrier-separated).
// Phase C: GEMM2 -> p2 (fp8) + selfp (f32).
__global__ __launch_bounds__(256) void agg_gemm12_kernel(
        const unsigned* __restrict__ xb, const int* __restrict__ rowptr,
        const int* __restrict__ cnt, const float* __restrict__ inv,
        const int* __restrict__ col,
        const unsigned short* __restrict__ WB1, const float* __restrict__ b1,
        const unsigned short* __restrict__ WB2, const float* __restrict__ b2,
        unsigned* __restrict__ p2, float* __restrict__ selfp, int N) {
    __shared__ unsigned short sh[64][136];   // A-tile, then h-tile (reused)
    __shared__ float st[64][41];
    int t = threadIdx.x;
    int g = t >> 3, chunk = t & 7;

    // ---- Phase A: aggregation ----
#pragma unroll
    for (int it = 0; it < 2; ++it) {
        int lr = it * 32 + g;
        int n = blockIdx.x * 64 + lr;
        float a[8];
#pragma unroll
        for (int j = 0; j < 8; j++) a[j] = 0.f;
        float invn = 0.f;
        uint4 u = make_uint4(0, 0, 0, 0);
        if (n < N) {
            int beg = rowptr[n], deg = cnt[n];
            int degp = (deg + 3) & ~3;
            for (int i = 0; i < degp; i += 4) {
                int s0 = col[beg + i], s1 = col[beg + i + 1];
                int s2 = col[beg + i + 2], s3 = col[beg + i + 3];
                uint4 u0 = *(const uint4*)(xb + (size_t)s0 * 32 + chunk * 4);
                uint4 u1 = *(const uint4*)(xb + (size_t)s1 * 32 + chunk * 4);
                uint4 u2 = *(const uint4*)(xb + (size_t)s2 * 32 + chunk * 4);
                uint4 u3 = *(const uint4*)(xb + (size_t)s3 * 32 + chunk * 4);
                a[0] += bflo(u0.x) + bflo(u1.x) + bflo(u2.x) + bflo(u3.x);
                a[1] += bfhi(u0.x) + bfhi(u1.x) + bfhi(u2.x) + bfhi(u3.x);
                a[2] += bflo(u0.y) + bflo(u1.y) + bflo(u2.y) + bflo(u3.y);
                a[3] += bfhi(u0.y) + bfhi(u1.y) + bfhi(u2.y) + bfhi(u3.y);
                a[4] += bflo(u0.z) + bflo(u1.z) + bflo(u2.z) + bflo(u3.z);
                a[5] += bfhi(u0.z) + bfhi(u1.z) + bfhi(u2.z) + bfhi(u3.z);
                a[6] += bflo(u0.w) + bflo(u1.w) + bflo(u2.w) + bflo(u3.w);
                a[7] += bfhi(u0.w) + bfhi(u1.w) + bfhi(u2.w) + bfhi(u3.w);
            }
            invn = inv[n];
            u = *(const uint4*)(xb + (size_t)n * 32 + chunk * 4);
        }
        uint4 o;
        o.x = bf16pair(a[0] * invn, a[1] * invn);
        o.y = bf16pair(a[2] * invn, a[3] * invn);
        o.z = bf16pair(a[4] * invn, a[5] * invn);
        o.w = bf16pair(a[6] * invn, a[7] * invn);
        *(uint4*)&sh[lr][chunk * 8] = o;        // agg half (cols 0..63)
        *(uint4*)&sh[lr][64 + chunk * 8] = u;   // self half (cols 64..127)
    }
    __syncthreads();

    // ---- Phase B: GEMM1 ----
    int w = t >> 6, lane = t & 63;
    int quad = lane >> 4, m = lane & 15;
    int rbase = blockIdx.x * 64 + w * 16;
    int lw = w * 16;

    f32x4 acc[8];
#pragma unroll
    for (int nt = 0; nt < 8; nt++) acc[nt] = (f32x4)(0.f);
#pragma unroll
    for (int ks = 0; ks < 4; ks++) {
        bf16x8 a = *(const bf16x8*)(&sh[lw + m][ks * 32 + quad * 8]);
#pragma unroll
        for (int nt = 0; nt < 8; nt++) {
            bf16x8 b = *(const bf16x8*)(WB1 + ((size_t)(nt * 4 + ks) * 64 + lane) * 8);
            acc[nt] = __builtin_amdgcn_mfma_f32_16x16x32_bf16(a, b, acc[nt], 0, 0, 0);
        }
    }
    __syncthreads();   // all A-reads done before overwriting sh with h
#pragma unroll
    for (int nt = 0; nt < 8; nt++) {
        int colj = nt * 16 + m;
        float bj = b1[colj];
#pragma unroll
        for (int r = 0; r < 4; r++) {
            sh[lw + quad * 4 + r][colj] = bf16r(fmaxf(acc[nt][r] + bj, 0.f));
        }
    }
    __syncthreads();

    // ---- Phase C: GEMM2 ----
    f32x4 acc2[5];
#pragma unroll
    for (int nt = 0; nt < 5; nt++) acc2[nt] = (f32x4)(0.f);
#pragma unroll
    for (int ks = 0; ks < 4; ks++) {
        bf16x8 a = *(const bf16x8*)(&sh[lw + m][ks * 32 + quad * 8]);
#pragma unroll
        for (int nt = 0; nt < 5; nt++) {
            bf16x8 b = *(const bf16x8*)(WB2 + ((size_t)(nt * 4 + ks) * 64 + lane) * 8);
            acc2[nt] = __builtin_amdgcn_mfma_f32_16x16x32_bf16(a, b, acc2[nt], 0, 0, 0);
        }
    }
#pragma unroll
    for (int nt = 0; nt < 5; nt++) {
        int colj = nt * 16 + m;
#pragma unroll
        for (int r = 0; r < 4; r++) {
            int lrow = lw + quad * 4 + r;
            int row = rbase + quad * 4 + r;
            float v = acc2[nt][r];
            if (colj < 40) {
                st[lrow][colj] = v;
            } else if (row < N) {
                selfp[(size_t)row * 40 + (colj - 40)] = v + b2[colj - 40];
            }
        }
    }
    __syncthreads();
    for (int i = t; i < 64 * 10; i += 256) {
        int lr = i / 10, dw = i - lr * 10;
        int grow = blockIdx.x * 64 + lr;
        if (grow < N) {
            float v0 = st[lr][dw * 4 + 0], v1 = st[lr][dw * 4 + 1];
            float v2 = st[lr][dw * 4 + 2], v3 = st[lr][dw * 4 + 3];
            unsigned u = __builtin_amdgcn_cvt_pk_fp8_f32(v0, v1, 0u, false);
            u = __builtin_amdgcn_cvt_pk_fp8_f32(v2, v3, u, true);
            p2[(size_t)grow * 10 + dw] = u;
        }
    }
}

// ---------- agg2 + log_softmax: 8 lanes/node (5 active), sequential edges 4-wide ----------
__global__ void agg2_softmax_kernel(const unsigned* __restrict__ p2,
                                    const float* __restrict__ selfp,
                                    const int* __restrict__ rowptr,
                                    const int* __restrict__ cnt,
                                    const float* __restrict__ inv,
                                    const int* __restrict__ col,
                                    float* __restrict__ out, int N) {
    int n = (blockIdx.x * 256 + threadIdx.x) >> 3;
    int chunk = threadIdx.x & 7;
    if (n >= N) return;
    int beg = rowptr[n], deg = cnt[n];
    int degp = (deg + 3) & ~3;
    bool vc = (chunk < 5);
    float a[8];
#pragma unroll
    for (int j = 0; j < 8; j++) a[j] = 0.f;
    for (int i = 0; i < degp; i += 4) {
        int s0 = col[beg + i], s1 = col[beg + i + 1];
        int s2 = col[beg + i + 2], s3 = col[beg + i + 3];
        if (vc) {
            uint2 u0 = *(const uint2*)(p2 + (size_t)s0 * 10 + chunk * 2);
            uint2 u1 = *(const uint2*)(p2 + (size_t)s1 * 10 + chunk * 2);
            uint2 u2 = *(const uint2*)(p2 + (size_t)s2 * 10 + chunk * 2);
            uint2 u3 = *(const uint2*)(p2 + (size_t)s3 * 10 + chunk * 2);
            f32x2 d;
            d = __builtin_amdgcn_cvt_pk_f32_fp8(u0.x, false); a[0] += d.x; a[1] += d.y;
            d = __builtin_amdgcn_cvt_pk_f32_fp8(u0.x, true);  a[2] += d.x; a[3] += d.y;
            d = __builtin_amdgcn_cvt_pk_f32_fp8(u0.y, false); a[4] += d.x; a[5] += d.y;
            d = __builtin_amdgcn_cvt_pk_f32_fp8(u0.y, true);  a[6] += d.x; a[7] += d.y;
            d = __builtin_amdgcn_cvt_pk_f32_fp8(u1.x, false); a[0] += d.x; a[1] += d.y;
            d = __builtin_amdgcn_cvt_pk_f32_fp8(u1.x, true);  a[2] += d.x; a[3] += d.y;
            d = __builtin_amdgcn_cvt_pk_f32_fp8(u1.y, false); a[4] += d.x; a[5] += d.y;
            d = __builtin_amdgcn_cvt_pk_f32_fp8(u1.y, true);  a[6] += d.x; a[7] += d.y;
            d = __builtin_amdgcn_cvt_pk_f32_fp8(u2.x, false); a[0] += d.x; a[1] += d.y;
            d = __builtin_amdgcn_cvt_pk_f32_fp8(u2.x, true);  a[2] += d.x; a[3] += d.y;
            d = __builtin_amdgcn_cvt_pk_f32_fp8(u2.y, false); a[4] += d.x; a[5] += d.y;
            d = __builtin_amdgcn_cvt_pk_f32_fp8(u2.y, true);  a[6] += d.x; a[7] += d.y;
            d = __builtin_amdgcn_cvt_pk_f32_fp8(u3.x, false); a[0] += d.x; a[1] += d.y;
            d = __builtin_amdgcn_cvt_pk_f32_fp8(u3.x, true);  a[2] += d.x; a[3] += d.y;
            d = __builtin_amdgcn_cvt_pk_f32_fp8(u3.y, false); a[4] += d.x; a[5] += d.y;
            d = __builtin_amdgcn_cvt_pk_f32_fp8(u3.y, true);  a[6] += d.x; a[7] += d.y;
        }
    }
    float invn = inv[n];
    float v[8];
    if (vc) {
        float4 s0 = *(const float4*)(selfp + (size_t)n * DO + chunk * 8);
        float4 s1 = *(const float4*)(selfp + (size_t)n * DO + chunk * 8 + 4);
        v[0] = a[0] * invn + s0.x; v[1] = a[1] * invn + s0.y;
        v[2] = a[2] * invn + s0.z; v[3] = a[3] * invn + s0.w;
        v[4] = a[4] * invn + s1.x; v[5] = a[5] * invn + s1.y;
        v[6] = a[6] * invn + s1.z; v[7] = a[7] * invn + s1.w;
    } else {
#pragma unroll
        for (int j = 0; j < 8; j++) v[j] = 0.f;
    }
    float mv = -INFINITY;
    if (vc) {
#pragma unroll
        for (int j = 0; j < 8; j++) mv = fmaxf(mv, v[j]);
    }
#pragma unroll
    for (int off = 1; off <= 4; off <<= 1) mv = fmaxf(mv, __shfl_xor(mv, off, 8));
    float es = 0.f;
    if (vc) {
#pragma unroll
        for (int j = 0; j < 8; j++) es += expf(v[j] - mv);
    }
#pragma unroll
    for (int off = 1; off <= 4; off <<= 1) es += __shfl_xor(es, off, 8);
    if (vc) {
        float ls = mv + logf(es);
        float4 o0, o1;
        o0.x = v[0] - ls; o0.y = v[1] - ls; o0.z = v[2] - ls; o0.w = v[3] - ls;
        o1.x = v[4] - ls; o1.y = v[5] - ls; o1.z = v[6] - ls; o1.w = v[7] - ls;
        *(float4*)(out + (size_t)n * DO + chunk * 8) = o0;
        *(float4*)(out + (size_t)n * DO + chunk * 8 + 4) = o1;
    }
}

extern "C" void kernel_launch(void* const* d_in, const int* in_sizes, int n_in,
                              void* d_out, int out_size, void* d_ws, size_t ws_size,
                              hipStream_t stream) {
    const float* x   = (const float*)d_in[0];
    const int*  ei   = (const int*)d_in[1];
    const float* W1l = (const float*)d_in[2];
    const float* b1  = (const float*)d_in[3];
    const float* W1r = (const float*)d_in[4];
    const float* W2l = (const float*)d_in[5];
    const float* b2  = (const float*)d_in[6];
    const float* W2r = (const float*)d_in[7];
    float* out = (float*)d_out;

    const int E = in_sizes[1] / 2;
    const int N = NN;
    const int* src = ei;
    const int* dst = ei + E;
    const int nbe = (E + EPB - 1) / EPB;
    const int nsetup = ((N + 1) * 32 + TPB_S - 1) / TPB_S;

    size_t off = 0;
    auto alloc = [&](size_t nf) { size_t o = off; off += (nf + 63) & ~(size_t)63; return o; };
    size_t o_bcur   = alloc(NBUCK);                   // int (counts, memset to 0)
    size_t o_eb     = alloc((size_t)NBUCK * CAP);     // int
    size_t o_col    = alloc((size_t)NBUCK * CAPP);    // int (padded CSR col)
    size_t o_rowptr = alloc(N);                       // int
    size_t o_cnt    = alloc(N);                       // int
    size_t o_inv    = alloc(N);                       // f32
    size_t o_xb     = alloc((size_t)(N + 1) * 32);    // u32 (64 bf16/row, +dummy)
    size_t o_p2     = alloc((size_t)(N + 1) * 10);    // u32 (40 fp8/row, +dummy) = 4MB
    size_t o_selfp  = alloc((size_t)N * DO);          // f32
    size_t o_wb1    = alloc(16384 / 2);
    size_t o_wb2    = alloc(10240 / 2);
    (void)ws_size;

    float* ws = (float*)d_ws;
    int* bcur   = (int*)(ws + o_bcur);
    int* eb     = (int*)(ws + o_eb);
    int* col    = (int*)(ws + o_col);
    int* rowptr = (int*)(ws + o_rowptr);
    int* cnt    = (int*)(ws + o_cnt);
    float* inv  = ws + o_inv;
    unsigned* xb = (unsigned*)(ws + o_xb);
    unsigned* p2 = (unsigned*)(ws + o_p2);
    float* selfp = ws + o_selfp;
    unsigned short* WB1 = (unsigned short*)(ws + o_wb1);
    unsigned short* WB2 = (unsigned short*)(ws + o_wb2);

    hipMemsetAsync(bcur, 0, NBUCK * sizeof(int), stream);

    setup_scatter_kernel<<<nbe + nsetup, TPB_S, 0, stream>>>(
        x, W1l, W1r, W2l, W2r, xb, WB1, WB2, p2, src, dst, bcur, eb, nbe, E, N);

    bucket_fill_kernel<<<NBUCK, 256, 0, stream>>>(eb, bcur, rowptr, cnt, inv, col, N);

    agg_gemm12_kernel<<<(N + 63) / 64, 256, 0, stream>>>(
        xb, rowptr, cnt, inv, col, WB1, b1, WB2, b2, p2, selfp, N);

    agg2_softmax_kernel<<<(N * 8 + 255) / 256, 256, 0, stream>>>(p2, selfp, rowptr, cnt, inv, col, out, N);
}

// Round 3
// 196.627 us; speedup vs baseline: 1.1716x; 1.0152x over previous
//
#include <hip/hip_runtime.h>
#include <math.h>

#define NN 100000
#define DI 64
#define DH 128
#define DO 40

#define NBUCK 512
#define NPB 196          // nodes per bucket: 512*196 = 100352 >= 100000
#define CAP 3712         // bucket capacity: mean 3125 + ~10.5 sigma
#define CAPP 5120        // padded col capacity: CAP + NPB*7 = 5084, rounded to 64
#define EPB 4096         // edges per scatter block
#define TPB_S 512        // threads per scatter/setup block
#define KE (EPB / TPB_S) // edges per thread = 8

typedef __attribute__((ext_vector_type(8))) short bf16x8;
typedef __attribute__((ext_vector_type(4))) float f32x4;
typedef __attribute__((ext_vector_type(2))) float f32x2;

__device__ __forceinline__ unsigned short bf16r(float a) {
    unsigned u = __float_as_uint(a);
    u = (u + 0x7FFF + ((u >> 16) & 1)) >> 16;
    return (unsigned short)u;
}
__device__ __forceinline__ unsigned bf16pair(float a, float b) {
    return (unsigned)bf16r(a) | ((unsigned)bf16r(b) << 16);
}
__device__ __forceinline__ float bflo(unsigned u) { return __uint_as_float(u << 16); }
__device__ __forceinline__ float bfhi(unsigned u) { return __uint_as_float(u & 0xFFFF0000u); }

// ---------- fused: scatter blocks [0,nbe) + setup blocks [nbe, nbe+nsetup) ----------
__global__ __launch_bounds__(TPB_S) void setup_scatter_kernel(
        const float* __restrict__ x, const float* __restrict__ W1l,
        const float* __restrict__ W1r, const float* __restrict__ W2l,
        const float* __restrict__ W2r,
        unsigned* __restrict__ xb, unsigned short* __restrict__ WB1,
        unsigned short* __restrict__ WB2, unsigned* __restrict__ p2,
        const int* __restrict__ src, const int* __restrict__ dst,
        int* __restrict__ bcur, int* __restrict__ eb,
        int nbe, int E, int N) {
    __shared__ int h[NBUCK];
    int t = threadIdx.x;
    if ((int)blockIdx.x < nbe) {
        // ---- bucket scatter: eb[pos] = (local<<17)|src ----
        if (t < NBUCK) h[t] = 0;
        __syncthreads();
        int base = blockIdx.x * EPB;
        int end = base + EPB; if (end > E) end = E;
        int dloc[KE];
#pragma unroll
        for (int k = 0; k < KE; k++) {
            int i = base + t + k * TPB_S;
            dloc[k] = (i < end) ? dst[i] : -1;
        }
#pragma unroll
        for (int k = 0; k < KE; k++)
            if (dloc[k] >= 0) atomicAdd(&h[(unsigned)dloc[k] / NPB], 1);
        __syncthreads();
        if (t < NBUCK) {
            int v = h[t];
            h[t] = v ? (atomicAdd(&bcur[t], v) + t * CAP) : 0;
        }
        __syncthreads();
#pragma unroll
        for (int k = 0; k < KE; k++) {
            int d = dloc[k];
            if (d >= 0) {
                unsigned bk = (unsigned)d / NPB;
                int local = d - (int)bk * NPB;
                int pos = atomicAdd(&h[bk], 1);
                eb[pos] = (local << 17) | src[base + t + k * TPB_S];
            }
        }
    } else {
        // ---- setup: x->bf16, weight packs, p2 dummy row ----
        int idx = (blockIdx.x - nbe) * TPB_S + t;
        if (idx < (N + 1) * 32) {
            if (idx < N * 32) {
                float2 f = ((const float2*)x)[idx];
                xb[idx] = bf16pair(f.x, f.y);
            } else {
                xb[idx] = 0;          // dummy row N of xb
            }
        }
        if (idx < 16384) {
            int j = idx & 7, lane = (idx >> 3) & 63, ks = (idx >> 9) & 3, nt = idx >> 11;
            int k = ks * 32 + (lane >> 4) * 8 + j;
            int n = nt * 16 + (lane & 15);
            float v = (k < DI) ? W1l[n * DI + k] : W1r[n * DI + (k - DI)];
            WB1[idx] = bf16r(v);
        }
        if (idx >= 16384 && idx < 16384 + 10240) {
            int idx2 = idx - 16384;
            int j = idx2 & 7, lane = (idx2 >> 3) & 63, ks = (idx2 >> 9) & 3, nt = idx2 >> 11;
            int k = ks * 32 + (lane >> 4) * 8 + j;
            int n = nt * 16 + (lane & 15);
            float v = (n < DO) ? W2l[n * DH + k] : W2r[(n - DO) * DH + k];
            WB2[idx2] = bf16r(v);
        }
        if (idx < 10) p2[(size_t)N * 10 + idx] = 0;   // dummy fp8 row N (decodes to 0)
    }
}

// ---------- fill: per bucket -> rowptr/cnt/inv + col padded to x8 with dummy NN ----------
__global__ __launch_bounds__(256) void bucket_fill_kernel(const int* __restrict__ eb,
                                                          const int* __restrict__ bend,
                                                          int* __restrict__ rowptr,
                                                          int* __restrict__ cntg,
                                                          float* __restrict__ inv,
                                                          int* __restrict__ col, int N) {
    __shared__ int scnt[256];
    __shared__ int scur[256];
    __shared__ int sbase[256];
    int b = blockIdx.x, t = threadIdx.x;
    int ebeg = b * CAP, eend = ebeg + bend[b];   // bend holds counts
    scnt[t] = 0;
    __syncthreads();
    for (int i = ebeg + t; i < eend; i += 256)
        atomicAdd(&scnt[eb[i] >> 17], 1);
    __syncthreads();
    int myc = scnt[t];
    int pc = (myc + 7) & ~7;                      // pad to x8 for 8-wide gathers
    scnt[t] = pc;
    __syncthreads();
    for (int off = 1; off < 256; off <<= 1) {
        int tmp = (t >= off) ? scnt[t - off] : 0;
        __syncthreads();
        scnt[t] += tmp;
        __syncthreads();
    }
    int excl = scnt[t] - pc;
    int base = b * CAPP + excl;
    int node = b * NPB + t;
    if (t < NPB && node < N) {
        rowptr[node] = base;
        cntg[node] = myc;
        inv[node] = 1.0f / (float)(myc > 0 ? myc : 1);
    }
    scur[t] = base;
    sbase[t] = base;
    __syncthreads();
    for (int i = ebeg + t; i < eend; i += 256) {
        int pk = eb[i];
        int pos = atomicAdd(&scur[pk >> 17], 1);
        col[pos] = pk & 0x1FFFF;
    }
    __syncthreads();
    if (t < NPB) {
        int bs = sbase[t];
        for (int i = myc; i < pc; i++) col[bs + i] = NN;
    }
}

// ---------- fused agg1 + GEMM1 + GEMM2: BARRIER-FREE, wave-private rows ----------
// Wave w owns rows [w*16, w*16+16) of the 64-row tile end-to-end:
//   Phase A: 8 groups x 8 lanes aggregate those 16 rows into sh.
//   Phase B: GEMM1 h=relu(A@Wcat1+b1), in place.
//   Phase C: GEMM2 -> p2 (fp8, staged via float alias of own sh rows) + selfp.
// Per-wave LDS ordering makes barriers unnecessary; fences stop TBAA reordering.
__global__ __launch_bounds__(256) void agg_gemm12_kernel(
        const unsigned* __restrict__ xb, const int* __restrict__ rowptr,
        const int* __restrict__ cnt, const float* __restrict__ inv,
        const int* __restrict__ col,
        const unsigned short* __restrict__ WB1, const float* __restrict__ b1,
        const unsigned short* __restrict__ WB2, const float* __restrict__ b2,
        unsigned* __restrict__ p2, float* __restrict__ selfp, int N) {
    __shared__ unsigned short sh[64][136];   // A-tile -> h-tile -> f32 stage (aliased)
    int t = threadIdx.x;
    int w = t >> 6, lane = t & 63;
    int lw = w * 16;
    int g8 = (t >> 3) & 7;                   // gather group within wave: 0..7
    int chunk = t & 7;
    int rbase = blockIdx.x * 64 + lw;

    // ---- Phase A: aggregate wave-private rows ----
#pragma unroll
    for (int it = 0; it < 2; ++it) {
        int lr = lw + g8 + it * 8;
        int n = blockIdx.x * 64 + lr;
        float a[8];
#pragma unroll
        for (int j = 0; j < 8; j++) a[j] = 0.f;
        float invn = 0.f;
        uint4 u = make_uint4(0, 0, 0, 0);
        if (n < N) {
            int beg = rowptr[n], deg = cnt[n];
            int degp = (deg + 3) & ~3;
            for (int i = 0; i < degp; i += 4) {
                int s0 = col[beg + i], s1 = col[beg + i + 1];
                int s2 = col[beg + i + 2], s3 = col[beg + i + 3];
                uint4 u0 = *(const uint4*)(xb + (size_t)s0 * 32 + chunk * 4);
                uint4 u1 = *(const uint4*)(xb + (size_t)s1 * 32 + chunk * 4);
                uint4 u2 = *(const uint4*)(xb + (size_t)s2 * 32 + chunk * 4);
                uint4 u3 = *(const uint4*)(xb + (size_t)s3 * 32 + chunk * 4);
                a[0] += bflo(u0.x) + bflo(u1.x) + bflo(u2.x) + bflo(u3.x);
                a[1] += bfhi(u0.x) + bfhi(u1.x) + bfhi(u2.x) + bfhi(u3.x);
                a[2] += bflo(u0.y) + bflo(u1.y) + bflo(u2.y) + bflo(u3.y);
                a[3] += bfhi(u0.y) + bfhi(u1.y) + bfhi(u2.y) + bfhi(u3.y);
                a[4] += bflo(u0.z) + bflo(u1.z) + bflo(u2.z) + bflo(u3.z);
                a[5] += bfhi(u0.z) + bfhi(u1.z) + bfhi(u2.z) + bfhi(u3.z);
                a[6] += bflo(u0.w) + bflo(u1.w) + bflo(u2.w) + bflo(u3.w);
                a[7] += bfhi(u0.w) + bfhi(u1.w) + bfhi(u2.w) + bfhi(u3.w);
            }
            invn = inv[n];
            u = *(const uint4*)(xb + (size_t)n * 32 + chunk * 4);
        }
        uint4 o;
        o.x = bf16pair(a[0] * invn, a[1] * invn);
        o.y = bf16pair(a[2] * invn, a[3] * invn);
        o.z = bf16pair(a[4] * invn, a[5] * invn);
        o.w = bf16pair(a[6] * invn, a[7] * invn);
        *(uint4*)&sh[lr][chunk * 8] = o;        // agg half (cols 0..63)
        *(uint4*)&sh[lr][64 + chunk * 8] = u;   // self half (cols 64..127)
    }
    asm volatile("" ::: "memory");

    // ---- Phase B: GEMM1 (reads/writes only own rows) ----
    int quad = lane >> 4, m = lane & 15;
    f32x4 acc[8];
#pragma unroll
    for (int nt = 0; nt < 8; nt++) acc[nt] = (f32x4)(0.f);
#pragma unroll
    for (int ks = 0; ks < 4; ks++) {
        bf16x8 a = *(const bf16x8*)(&sh[lw + m][ks * 32 + quad * 8]);
#pragma unroll
        for (int nt = 0; nt < 8; nt++) {
            bf16x8 b = *(const bf16x8*)(WB1 + ((size_t)(nt * 4 + ks) * 64 + lane) * 8);
            acc[nt] = __builtin_amdgcn_mfma_f32_16x16x32_bf16(a, b, acc[nt], 0, 0, 0);
        }
    }
    asm volatile("" ::: "memory");
#pragma unroll
    for (int nt = 0; nt < 8; nt++) {
        int colj = nt * 16 + m;
        float bj = b1[colj];
#pragma unroll
        for (int r = 0; r < 4; r++) {
            sh[lw + quad * 4 + r][colj] = bf16r(fmaxf(acc[nt][r] + bj, 0.f));
        }
    }
    asm volatile("" ::: "memory");

    // ---- Phase C: GEMM2 ----
    f32x4 acc2[5];
#pragma unroll
    for (int nt = 0; nt < 5; nt++) acc2[nt] = (f32x4)(0.f);
#pragma unroll
    for (int ks = 0; ks < 4; ks++) {
        bf16x8 a = *(const bf16x8*)(&sh[lw + m][ks * 32 + quad * 8]);
#pragma unroll
        for (int nt = 0; nt < 5; nt++) {
            bf16x8 b = *(const bf16x8*)(WB2 + ((size_t)(nt * 4 + ks) * 64 + lane) * 8);
            acc2[nt] = __builtin_amdgcn_mfma_f32_16x16x32_bf16(a, b, acc2[nt], 0, 0, 0);
        }
    }
    asm volatile("" ::: "memory");
    float* stw = (float*)&sh[lw][0];         // 16 rows x 41 f32 = 2624 B <= 4352 B
#pragma unroll
    for (int nt = 0; nt < 5; nt++) {
        int colj = nt * 16 + m;
#pragma unroll
        for (int r = 0; r < 4; r++) {
            int row = rbase + quad * 4 + r;
            float v = acc2[nt][r];
            if (colj < 40) {
                stw[(quad * 4 + r) * 41 + colj] = v;
            } else if (row < N) {
                selfp[(size_t)row * 40 + (colj - 40)] = v + b2[colj - 40];
            }
        }
    }
    asm volatile("" ::: "memory");
    for (int i = lane; i < 160; i += 64) {
        int lr = i / 10, dw = i - lr * 10;
        int grow = rbase + lr;
        if (grow < N) {
            float v0 = stw[lr * 41 + dw * 4 + 0], v1 = stw[lr * 41 + dw * 4 + 1];
            float v2 = stw[lr * 41 + dw * 4 + 2], v3 = stw[lr * 41 + dw * 4 + 3];
            unsigned u = __builtin_amdgcn_cvt_pk_fp8_f32(v0, v1, 0u, false);
            u = __builtin_amdgcn_cvt_pk_fp8_f32(v2, v3, u, true);
            p2[(size_t)grow * 10 + dw] = u;
        }
    }
}

// ---------- agg2 + log_softmax: 8 lanes/node (5 active), edges 8-wide ----------
__global__ void agg2_softmax_kernel(const unsigned* __restrict__ p2,
                                    const float* __restrict__ selfp,
                                    const int* __restrict__ rowptr,
                                    const int* __restrict__ cnt,
                                    const float* __restrict__ inv,
                                    const int* __restrict__ col,
                                    float* __restrict__ out, int N) {
    int n = (blockIdx.x * 256 + threadIdx.x) >> 3;
    int chunk = threadIdx.x & 7;
    if (n >= N) return;
    int beg = rowptr[n], deg = cnt[n];
    int degp = (deg + 7) & ~7;
    bool vc = (chunk < 5);
    float a[8];
#pragma unroll
    for (int j = 0; j < 8; j++) a[j] = 0.f;
    for (int i = 0; i < degp; i += 8) {
        int ss[8];
#pragma unroll
        for (int k = 0; k < 8; k++) ss[k] = col[beg + i + k];
        if (vc) {
            uint2 uu[8];
#pragma unroll
            for (int k = 0; k < 8; k++)
                uu[k] = *(const uint2*)(p2 + (size_t)ss[k] * 10 + chunk * 2);
#pragma unroll
            for (int k = 0; k < 8; k++) {
                f32x2 d;
                d = __builtin_amdgcn_cvt_pk_f32_fp8(uu[k].x, false); a[0] += d.x; a[1] += d.y;
                d = __builtin_amdgcn_cvt_pk_f32_fp8(uu[k].x, true);  a[2] += d.x; a[3] += d.y;
                d = __builtin_amdgcn_cvt_pk_f32_fp8(uu[k].y, false); a[4] += d.x; a[5] += d.y;
                d = __builtin_amdgcn_cvt_pk_f32_fp8(uu[k].y, true);  a[6] += d.x; a[7] += d.y;
            }
        }
    }
    float invn = inv[n];
    float v[8];
    if (vc) {
        float4 s0 = *(const float4*)(selfp + (size_t)n * DO + chunk * 8);
        float4 s1 = *(const float4*)(selfp + (size_t)n * DO + chunk * 8 + 4);
        v[0] = a[0] * invn + s0.x; v[1] = a[1] * invn + s0.y;
        v[2] = a[2] * invn + s0.z; v[3] = a[3] * invn + s0.w;
        v[4] = a[4] * invn + s1.x; v[5] = a[5] * invn + s1.y;
        v[6] = a[6] * invn + s1.z; v[7] = a[7] * invn + s1.w;
    } else {
#pragma unroll
        for (int j = 0; j < 8; j++) v[j] = 0.f;
    }
    float mv = -INFINITY;
    if (vc) {
#pragma unroll
        for (int j = 0; j < 8; j++) mv = fmaxf(mv, v[j]);
    }
#pragma unroll
    for (int off = 1; off <= 4; off <<= 1) mv = fmaxf(mv, __shfl_xor(mv, off, 8));
    float es = 0.f;
    if (vc) {
#pragma unroll
        for (int j = 0; j < 8; j++) es += expf(v[j] - mv);
    }
#pragma unroll
    for (int off = 1; off <= 4; off <<= 1) es += __shfl_xor(es, off, 8);
    if (vc) {
        float ls = mv + logf(es);
        float4 o0, o1;
        o0.x = v[0] - ls; o0.y = v[1] - ls; o0.z = v[2] - ls; o0.w = v[3] - ls;
        o1.x = v[4] - ls; o1.y = v[5] - ls; o1.z = v[6] - ls; o1.w = v[7] - ls;
        *(float4*)(out + (size_t)n * DO + chunk * 8) = o0;
        *(float4*)(out + (size_t)n * DO + chunk * 8 + 4) = o1;
    }
}

extern "C" void kernel_launch(void* const* d_in, const int* in_sizes, int n_in,
                              void* d_out, int out_size, void* d_ws, size_t ws_size,
                              hipStream_t stream) {
    const float* x   = (const float*)d_in[0];
    const int*  ei   = (const int*)d_in[1];
    const float* W1l = (const float*)d_in[2];
    const float* b1  = (const float*)d_in[3];
    const float* W1r = (const float*)d_in[4];
    const float* W2l = (const float*)d_in[5];
    const float* b2  = (const float*)d_in[6];
    const float* W2r = (const float*)d_in[7];
    float* out = (float*)d_out;

    const int E = in_sizes[1] / 2;
    const int N = NN;
    const int* src = ei;
    const int* dst = ei + E;
    const int nbe = (E + EPB - 1) / EPB;
    const int nsetup = ((N + 1) * 32 + TPB_S - 1) / TPB_S;

    size_t off = 0;
    auto alloc = [&](size_t nf) { size_t o = off; off += (nf + 63) & ~(size_t)63; return o; };
    size_t o_bcur   = alloc(NBUCK);                   // int (counts, memset to 0)
    size_t o_eb     = alloc((size_t)NBUCK * CAP);     // int
    size_t o_col    = alloc((size_t)NBUCK * CAPP);    // int (padded CSR col)
    size_t o_rowptr = alloc(N);                       // int
    size_t o_cnt    = alloc(N);                       // int
    size_t o_inv    = alloc(N);                       // f32
    size_t o_xb     = alloc((size_t)(N + 1) * 32);    // u32 (64 bf16/row, +dummy)
    size_t o_p2     = alloc((size_t)(N + 1) * 10);    // u32 (40 fp8/row, +dummy) = 4MB
    size_t o_selfp  = alloc((size_t)N * DO);          // f32
    size_t o_wb1    = alloc(16384 / 2);
    size_t o_wb2    = alloc(10240 / 2);
    (void)ws_size;

    float* ws = (float*)d_ws;
    int* bcur   = (int*)(ws + o_bcur);
    int* eb     = (int*)(ws + o_eb);
    int* col    = (int*)(ws + o_col);
    int* rowptr = (int*)(ws + o_rowptr);
    int* cnt    = (int*)(ws + o_cnt);
    float* inv  = ws + o_inv;
    unsigned* xb = (unsigned*)(ws + o_xb);
    unsigned* p2 = (unsigned*)(ws + o_p2);
    float* selfp = ws + o_selfp;
    unsigned short* WB1 = (unsigned short*)(ws + o_wb1);
    unsigned short* WB2 = (unsigned short*)(ws + o_wb2);

    hipMemsetAsync(bcur, 0, NBUCK * sizeof(int), stream);

    setup_scatter_kernel<<<nbe + nsetup, TPB_S, 0, stream>>>(
        x, W1l, W1r, W2l, W2r, xb, WB1, WB2, p2, src, dst, bcur, eb, nbe, E, N);

    bucket_fill_kernel<<<NBUCK, 256, 0, stream>>>(eb, bcur, rowptr, cnt, inv, col, N);

    agg_gemm12_kernel<<<(N + 63) / 64, 256, 0, stream>>>(
        xb, rowptr, cnt, inv, col, WB1, b1, WB2, b2, p2, selfp, N);

    agg2_softmax_kernel<<<(N * 8 + 255) / 256, 256, 0, stream>>>(p2, selfp, rowptr, cnt, inv, col, out, N);
}